// Round 13
// baseline (121.450 us; speedup 1.0000x reference)
//
#include <hip/hip_runtime.h>
#include <hip/hip_bf16.h>
#include <cstdint>

// Problem constants (fixed by setup_inputs)
#define B_     32
#define T_     4096
#define C_     256
#define BM     64    // time rows per tile
#define DMAX   8     // max supported dilation (problem uses 4)
#define NROWS  (BM + DMAX)   // 72 LDS rows per buffer

typedef __attribute__((ext_vector_type(8))) short bf16x8;
typedef __attribute__((ext_vector_type(4))) float f32x4;
typedef __attribute__((ext_vector_type(4))) short s16x4;

static __device__ __forceinline__ short f2bf(float f) {
  __hip_bfloat16 h = __float2bfloat16(f);
  union { __hip_bfloat16 h; short s; } u; u.h = h;
  return u.s;
}

static __device__ __forceinline__ float rcp_(float x) {
  return __builtin_amdgcn_rcpf(x);
}

// ---------------------------------------------------------------------------
// Prep: bf16 weight image, LINEAR layout for direct per-lane fragment loads:
//   wimg[((nb*16 + ks)*256 + np)*32 + kk]   (shorts)
// nb = N-half, ks = k-step (K=32), np = local col (0..127 value, 128..255
// gate), kk = k within step. k = 32*ks + kk: k<256 -> tap0, else tap1.
// ---------------------------------------------------------------------------
__global__ void prep_weights(const float* __restrict__ Wv, const float* __restrict__ Wg,
                             const float* __restrict__ bv, const float* __restrict__ bg,
                             short* __restrict__ wimg, float* __restrict__ bcat) {
  int id = blockIdx.x * 256 + threadIdx.x;   // 2*16*256*32 = 262144 total
  int kk = id & 31;
  int np = (id >> 5) & 255;
  int ks = (id >> 13) & 15;
  int nb = id >> 17;
  int k = ks * 32 + kk, tap = k >> 8, kr = k & 255;
  int sel = np >> 7;
  int f = nb * 128 + (np & 127);
  const float* W = sel ? Wg : Wv;
  wimg[id] = f2bf(W[((size_t)tap * 256 + kr) * 256 + f]);
  if (id < 512) bcat[id] = (id < 256) ? bv[id] : bg[id - 256];
}

// ---------------------------------------------------------------------------
// Main: 512 threads = 8 waves, 1x8 N-partition (round-9 economics: per wave
// per k-step 4x 1KB coalesced weight loads + 16 MFMA, acc=64, no dup).
// Two consecutive tiles per block, double-buffered LDS; tile1 staging
// interleaved with tile0 epilogue (r12 structure). REGISTER DIET vs r12:
// no k-loop weight ping-pong (-32 regs) so arch+acc <= 124 -> 4 waves/SIMD
// -> 2 blocks/CU (r12 was 132 -> 3 waves -> 1 block/CU, the regression).
// ---------------------------------------------------------------------------
__global__ __launch_bounds__(512, 4) void snail_main(
    const float* __restrict__ x, const short* __restrict__ wimg,
    const float* __restrict__ bcat, const int* __restrict__ dptr,
    float* __restrict__ out) {
  __shared__ __align__(16) short lx[2][NROWS * C_];   // 2 x 36 KiB, swizzled

  const int d = *dptr;                    // problem: 4 (<= DMAX)
  const int bid = blockIdx.x;
  const int swz = (bid & 7) * 128 + (bid >> 3);   // 1024 blocks, bijective
  const int b    = swz >> 5;              // batch
  const int t0   = (swz & 31) * (2 * BM); // first tile base
  const int t1   = t0 + BM;               // second tile base

  const int tid  = threadIdx.x;
  const int lane = tid & 63;
  const int w    = tid >> 6;
  const int nb   = w >> 2;                // N-half owned by this wave
  const int wq   = w & 3;                 // quarter within the half
  const int row15 = lane & 15;
  const int qw    = lane >> 4;
  const int srow  = tid >> 6;             // staging: row within 8-row chunk
  const int sc4   = tid & 63;             // staging: f32x4 unit within row

  const float* xb = x + (size_t)b * T_ * C_;
  float* ob = out + (size_t)b * T_ * 512;

  // per-lane weight base: np = wq*32 + row15 (value), kk = qw*8
  const short* wl = wimg + (size_t)nb * 131072 + (wq * 32 + row15) * 32 + qw * 8;

  f32x4 accv[4][2], accg[4][2];

#define CH_LOAD(REG, Cc, TB) do {                                       \
    int r_ = (Cc) * 8 + srow;                                           \
    int t_ = (TB) - d + r_;                                             \
    REG = (f32x4){0.f, 0.f, 0.f, 0.f};                                  \
    if (r_ < BM + d && t_ >= 0)                                         \
      REG = *(const f32x4*)(xb + (size_t)t_ * C_ + sc4 * 4);            \
  } while (0)

#define CH_FIN(REG, Cc, TB, NBUF) do {                                  \
    int r_ = (Cc) * 8 + srow;                                           \
    if (r_ < BM + d) {                                                  \
      int t_ = (TB) - d + r_;                                           \
      if (r_ >= d)                                                      \
        __builtin_nontemporal_store(REG,                                \
            (f32x4*)(ob + (size_t)t_ * 512 + C_ + sc4 * 4));            \
      s16x4 s_;                                                         \
      s_.x = f2bf(REG.x); s_.y = f2bf(REG.y);                           \
      s_.z = f2bf(REG.z); s_.w = f2bf(REG.w);                           \
      int byte_ = (r_ * 512 + sc4 * 8) ^ ((r_ & 7) << 4);               \
      *(s16x4*)((char*)&lx[NBUF][0] + byte_) = s_;                      \
    }                                                                   \
  } while (0)

#define STEP(BASE, KS) do {                                             \
    const short* wk_ = wl + (KS) * 8192;                                \
    bf16x8 w0 = *(const bf16x8*)(wk_);                                  \
    bf16x8 w1 = *(const bf16x8*)(wk_ + 512);                            \
    bf16x8 w2 = *(const bf16x8*)(wk_ + 4096);                           \
    bf16x8 w3 = *(const bf16x8*)(wk_ + 4608);                           \
    bf16x8 af[4];                                                       \
    const int rofs_ = ((KS) >= 8) ? d : 0;                              \
    const int cb_ = ((KS) & 7) * 64 + qw * 16;                          \
    _Pragma("unroll")                                                   \
    for (int mi = 0; mi < 4; ++mi) {                                    \
      int r_ = 16 * mi + row15 + rofs_;                                 \
      af[mi] = *(const bf16x8*)((BASE) +                                \
               ((r_ * 512 + cb_) ^ ((r_ & 7) << 4)));                   \
    }                                                                   \
    _Pragma("unroll")                                                   \
    for (int mi = 0; mi < 4; ++mi) {                                    \
      accv[mi][0] = __builtin_amdgcn_mfma_f32_16x16x32_bf16(w0, af[mi], accv[mi][0], 0, 0, 0); \
      accv[mi][1] = __builtin_amdgcn_mfma_f32_16x16x32_bf16(w1, af[mi], accv[mi][1], 0, 0, 0); \
      accg[mi][0] = __builtin_amdgcn_mfma_f32_16x16x32_bf16(w2, af[mi], accg[mi][0], 0, 0, 0); \
      accg[mi][1] = __builtin_amdgcn_mfma_f32_16x16x32_bf16(w3, af[mi], accg[mi][1], 0, 0, 0); \
    }                                                                   \
  } while (0)

#define ZERO_ACC do {                                                   \
    _Pragma("unroll")                                                   \
    for (int mi = 0; mi < 4; ++mi)                                      \
      _Pragma("unroll")                                                 \
      for (int ni = 0; ni < 2; ++ni) {                                  \
        accv[mi][ni] = (f32x4){0.f, 0.f, 0.f, 0.f};                     \
        accg[mi][ni] = (f32x4){0.f, 0.f, 0.f, 0.f};                     \
      }                                                                 \
  } while (0)

#define KLOOP(BUF) do {                                                 \
    const char* base_ = (const char*)&lx[BUF][0];                       \
    _Pragma("unroll 2")                                                 \
    for (int ks = 0; ks < 16; ++ks) STEP(base_, ks);                    \
  } while (0)

  // one epilogue unit: 4 output elems, tanh*sigmoid = (e2v-1)*rcp((e2v+1)(1+eng))
#define EPI(TB, NI, MI) do {                                            \
    int f0_ = nb * 128 + wq * 32 + 16 * (NI) + qw * 4;                  \
    f32x4 bv4_ = *(const f32x4*)(bcat + f0_);                           \
    f32x4 bg4_ = *(const f32x4*)(bcat + 256 + f0_);                     \
    int t_ = (TB) + 16 * (MI) + row15;                                  \
    f32x4 v_ = accv[MI][NI], g_ = accg[MI][NI];                         \
    f32x4 res_;                                                         \
    _Pragma("unroll")                                                   \
    for (int j = 0; j < 4; ++j) {                                       \
      float e2v = __expf(__builtin_fmaf(v_[j], 2.f, bv4_[j] + bv4_[j])); \
      float eng = __expf(__builtin_fmaf(g_[j], -1.f, -bg4_[j]));        \
      res_[j] = (e2v - 1.f) * rcp_((e2v + 1.f) * (1.f + eng));          \
    }                                                                   \
    __builtin_nontemporal_store(res_, (f32x4*)(ob + (size_t)t_ * 512 + f0_)); \
  } while (0)

  // ---- prologue: stage tile0 -> buf0 (3 groups of 3 chunks)
  {
    f32x4 p0, p1, p2;
    CH_LOAD(p0, 0, t0); CH_LOAD(p1, 1, t0); CH_LOAD(p2, 2, t0);
    CH_FIN(p0, 0, t0, 0); CH_FIN(p1, 1, t0, 0); CH_FIN(p2, 2, t0, 0);
    CH_LOAD(p0, 3, t0); CH_LOAD(p1, 4, t0); CH_LOAD(p2, 5, t0);
    CH_FIN(p0, 3, t0, 0); CH_FIN(p1, 4, t0, 0); CH_FIN(p2, 5, t0, 0);
    CH_LOAD(p0, 6, t0); CH_LOAD(p1, 7, t0); CH_LOAD(p2, 8, t0);
    CH_FIN(p0, 6, t0, 0); CH_FIN(p1, 7, t0, 0); CH_FIN(p2, 8, t0, 0);
  }
  __syncthreads();

  // ---- tile0 compute
  ZERO_ACC;
  KLOOP(0);
  // (no barrier: kloop read buf0; staging below writes buf1 — disjoint)

  // ---- tile0 epilogue INTERLEAVED with tile1 staging -> buf1
  {
    f32x4 s0, s1, s2;
    CH_LOAD(s0, 0, t1); CH_LOAD(s1, 1, t1); CH_LOAD(s2, 8, t1);
    EPI(t0, 0, 0); EPI(t0, 0, 1);
    CH_FIN(s0, 0, t1, 1); CH_FIN(s1, 1, t1, 1);
    CH_LOAD(s0, 2, t1); CH_LOAD(s1, 3, t1);
    EPI(t0, 0, 2); EPI(t0, 0, 3);
    CH_FIN(s0, 2, t1, 1); CH_FIN(s1, 3, t1, 1);
    CH_LOAD(s0, 4, t1); CH_LOAD(s1, 5, t1);
    EPI(t0, 1, 0); EPI(t0, 1, 1);
    CH_FIN(s0, 4, t1, 1); CH_FIN(s1, 5, t1, 1);
    CH_LOAD(s0, 6, t1); CH_LOAD(s1, 7, t1);
    EPI(t0, 1, 2); EPI(t0, 1, 3);
    CH_FIN(s0, 6, t1, 1); CH_FIN(s1, 7, t1, 1);
    CH_FIN(s2, 8, t1, 1);
  }
  __syncthreads();   // buf1 fully staged

  // ---- tile1 compute + plain epilogue
  ZERO_ACC;
  KLOOP(1);
  EPI(t1, 0, 0); EPI(t1, 0, 1); EPI(t1, 0, 2); EPI(t1, 0, 3);
  EPI(t1, 1, 0); EPI(t1, 1, 1); EPI(t1, 1, 2); EPI(t1, 1, 3);

#undef CH_LOAD
#undef CH_FIN
#undef STEP
#undef ZERO_ACC
#undef KLOOP
#undef EPI
}

extern "C" void kernel_launch(void* const* d_in, const int* in_sizes, int n_in,
                              void* d_out, int out_size, void* d_ws, size_t ws_size,
                              hipStream_t stream) {
  const float* x  = (const float*)d_in[0];
  const float* Wv = (const float*)d_in[1];
  const float* bv = (const float*)d_in[2];
  const float* Wg = (const float*)d_in[3];
  const float* bg = (const float*)d_in[4];
  const int* dil  = (const int*)d_in[5];
  float* out = (float*)d_out;

  short* wimg = (short*)d_ws;                          // 512 KiB weight image
  float* bcat = (float*)((char*)d_ws + 16 * 32768);    // 2 KiB biases

  prep_weights<<<1024, 256, 0, stream>>>(Wv, Wg, bv, bg, wimg, bcat);
  snail_main<<<B_ * (T_ / BM) / 2, 512, 0, stream>>>(x, wimg, bcat, dil, out);
}

// Round 14
// 111.550 us; speedup vs baseline: 1.0888x; 1.0888x over previous
//
#include <hip/hip_runtime.h>
#include <hip/hip_bf16.h>
#include <cstdint>

// Problem constants (fixed by setup_inputs)
#define B_    32
#define T_    4096
#define C_    256
#define BM    64     // time rows per block
#define DMAX  16     // max supported dilation (problem uses 4)
#define NROWS (BM + DMAX)

typedef __attribute__((ext_vector_type(8))) short bf16x8;
typedef __attribute__((ext_vector_type(4))) float f32x4;
typedef __attribute__((ext_vector_type(4))) short s16x4;

static __device__ __forceinline__ short f2bf(float f) {
  __hip_bfloat16 h = __float2bfloat16(f);
  union { __hip_bfloat16 h; short s; } u; u.h = h;
  return u.s;
}

static __device__ __forceinline__ float rcp_(float x) {
  return __builtin_amdgcn_rcpf(x);
}

// ---------------------------------------------------------------------------
// Prep: bf16 weight image, LINEAR layout for direct per-lane fragment loads:
//   wimg[((nb*16 + ks)*256 + np)*32 + kk]   (shorts)
// nb = N-half, ks = k-step (K=32), np = local col (0..127 value, 128..255
// gate), kk = k within step. k = 32*ks + kk: k<256 -> tap0, else tap1.
// ---------------------------------------------------------------------------
__global__ void prep_weights(const float* __restrict__ Wv, const float* __restrict__ Wg,
                             const float* __restrict__ bv, const float* __restrict__ bg,
                             short* __restrict__ wimg, float* __restrict__ bcat) {
  int id = blockIdx.x * 256 + threadIdx.x;   // 2*16*256*32 = 262144 total
  int kk = id & 31;
  int np = (id >> 5) & 255;
  int ks = (id >> 13) & 15;
  int nb = id >> 17;
  int k = ks * 32 + kk, tap = k >> 8, kr = k & 255;
  int sel = np >> 7;
  int f = nb * 128 + (np & 127);
  const float* W = sel ? Wg : Wv;
  wimg[id] = f2bf(W[((size_t)tap * 256 + kr) * 256 + f]);
  if (id < 512) bcat[id] = (id < 256) ? bv[id] : bg[id - 256];
}

// ---------------------------------------------------------------------------
// Main (round-9 winner + T5 setprio): 512 threads = 8 waves, 1x8 N-partition
// (wave w -> nb = w>>2, value np [32(w&3),+32), gate np +128; per k-step each
// wave: 4x 1KB coalesced weight loads + 16 MFMA; acc=64; no duplication).
// x staged ONCE per tile; k-loop BARRIER-FREE with register ping-pong weight
// prefetch. NEW: s_setprio(1) around each MFMA cluster — waves in the k-loop
// win issue arbitration over co-resident waves doing stage/epilogue (T5;
// applies here because blocks are independent & barrier-free, unlike m190's
// lockstep GEMM). Transposed MFMA -> float4 nt-stores.
// ---------------------------------------------------------------------------
__global__ __launch_bounds__(512, 4) void snail_main(
    const float* __restrict__ x, const short* __restrict__ wimg,
    const float* __restrict__ bcat, const int* __restrict__ dptr,
    float* __restrict__ out) {
  __shared__ __align__(16) short lx[NROWS * C_];   // 40 KiB, swizzled bf16 x-tile

  const int d = *dptr;
  // XCD-aware bijective swizzle (2048 blocks, 2048 % 8 == 0)
  const int bid = blockIdx.x;
  const int swz = (bid & 7) * 256 + (bid >> 3);
  const int t0 = (swz & 63) * BM;  // time tile
  const int b  = swz >> 6;         // batch

  const int tid  = threadIdx.x;
  const int lane = tid & 63;
  const int w    = tid >> 6;
  const int nb   = w >> 2;         // N-half owned by this wave
  const int wq   = w & 3;          // quarter within the half
  const int row15 = lane & 15;
  const int qw    = lane >> 4;

  const float* xb = x + (size_t)b * T_ * C_;
  float* ob = out + (size_t)b * T_ * 512;

  // ---- stage x rows t0-d..t0+BM-1 into LDS (bf16, swizzled) once per tile;
  //      fuse the exact fp32 passthrough (full rows, contiguous).
  for (int i = tid; i < d * 64; i += 512) {          // prefix rows [0,d)
    int r = i >> 6, c4 = i & 63;
    int t = t0 - d + r;
    f32x4 v = (f32x4){0.f, 0.f, 0.f, 0.f};
    if (t >= 0) v = *(const f32x4*)(xb + (size_t)t * C_ + c4 * 4);
    s16x4 s;
    s.x = f2bf(v.x); s.y = f2bf(v.y); s.z = f2bf(v.z); s.w = f2bf(v.w);
    int byte = (r * 512 + c4 * 8) ^ ((r & 7) << 4);
    *(s16x4*)((char*)lx + byte) = s;
  }
#pragma unroll 4
  for (int ii = 0; ii < 8; ++ii) {                   // main rows [d, d+BM)
    int i = ii * 512 + tid;
    int rr = i >> 6, c4 = i & 63;
    int t = t0 + rr, r = rr + d;
    f32x4 v = *(const f32x4*)(xb + (size_t)t * C_ + c4 * 4);
    __builtin_nontemporal_store(v, (f32x4*)(ob + (size_t)t * 512 + C_ + c4 * 4));
    s16x4 s;
    s.x = f2bf(v.x); s.y = f2bf(v.y); s.z = f2bf(v.z); s.w = f2bf(v.w);
    int byte = (r * 512 + c4 * 8) ^ ((r & 7) << 4);
    *(s16x4*)((char*)lx + byte) = s;
  }
  __syncthreads();   // the ONLY barrier

  f32x4 accv[4][2], accg[4][2];
#pragma unroll
  for (int mi = 0; mi < 4; ++mi)
#pragma unroll
    for (int ni = 0; ni < 2; ++ni) {
      accv[mi][ni] = (f32x4){0.f, 0.f, 0.f, 0.f};
      accg[mi][ni] = (f32x4){0.f, 0.f, 0.f, 0.f};
    }

  // per-lane weight base: np = wq*32 + row15 (value), kk = qw*8
  const short* wl = wimg + (size_t)nb * 131072 + (wq * 32 + row15) * 32 + qw * 8;

#define LOADW(D0, D1, D2, D3, KS) do {                                  \
    const short* wk_ = wl + (KS) * 8192;                                \
    D0 = *(const bf16x8*)(wk_);                                         \
    D1 = *(const bf16x8*)(wk_ + 512);                                   \
    D2 = *(const bf16x8*)(wk_ + 4096);                                  \
    D3 = *(const bf16x8*)(wk_ + 4608);                                  \
  } while (0)

#define STEP(B0, B1, G0, G1, KS) do {                                   \
    bf16x8 af[4];                                                       \
    const int rofs_ = ((KS) >= 8) ? d : 0;                              \
    const int cb_ = ((KS) & 7) * 64 + qw * 16;                          \
    _Pragma("unroll")                                                   \
    for (int mi = 0; mi < 4; ++mi) {                                    \
      int r_ = 16 * mi + row15 + rofs_;                                 \
      af[mi] = *(const bf16x8*)((const char*)lx +                       \
               ((r_ * 512 + cb_) ^ ((r_ & 7) << 4)));                   \
    }                                                                   \
    __builtin_amdgcn_s_setprio(1);                                      \
    _Pragma("unroll")                                                   \
    for (int mi = 0; mi < 4; ++mi) {                                    \
      accv[mi][0] = __builtin_amdgcn_mfma_f32_16x16x32_bf16(B0, af[mi], accv[mi][0], 0, 0, 0); \
      accv[mi][1] = __builtin_amdgcn_mfma_f32_16x16x32_bf16(B1, af[mi], accv[mi][1], 0, 0, 0); \
      accg[mi][0] = __builtin_amdgcn_mfma_f32_16x16x32_bf16(G0, af[mi], accg[mi][0], 0, 0, 0); \
      accg[mi][1] = __builtin_amdgcn_mfma_f32_16x16x32_bf16(G1, af[mi], accg[mi][1], 0, 0, 0); \
    }                                                                   \
    __builtin_amdgcn_s_setprio(0);                                      \
  } while (0)

  bf16x8 a0, a1, a2, a3, b0, b1, b2, b3;
  LOADW(a0, a1, a2, a3, 0);
#pragma unroll 1
  for (int ks2 = 0; ks2 < 8; ++ks2) {
    LOADW(b0, b1, b2, b3, 2 * ks2 + 1);   // prefetch odd step
    STEP(a0, a1, a2, a3, 2 * ks2);        // compute even step (loads in flight)
    if (ks2 < 7) LOADW(a0, a1, a2, a3, 2 * ks2 + 2);  // prefetch next even
    STEP(b0, b1, b2, b3, 2 * ks2 + 1);    // compute odd step
  }
#undef LOADW
#undef STEP

  // ---- epilogue: out[t][f] = tanh(v+bv)*sigmoid(g+bg)
  //      = (e2v-1) * rcp((e2v+1)*(1+eng)), e2v=exp(2(v+bv)), eng=exp(-(g+bg))
  //      D^T layout: t = t0+16mi+row15 ; f = nb*128 + wq*32 + 16ni + qw*4 + j
#pragma unroll
  for (int ni = 0; ni < 2; ++ni) {
    int f0 = nb * 128 + wq * 32 + 16 * ni + qw * 4;
    f32x4 bv4 = *(const f32x4*)(bcat + f0);
    f32x4 bg4 = *(const f32x4*)(bcat + 256 + f0);
    f32x4 bv2 = bv4 + bv4;     // 2*bias_v
    f32x4 bgn = -bg4;          // -bias_g
#pragma unroll
    for (int mi = 0; mi < 4; ++mi) {
      int t = t0 + 16 * mi + row15;
      f32x4 v = accv[mi][ni], g = accg[mi][ni];
      f32x4 res;
#pragma unroll
      for (int j = 0; j < 4; ++j) {
        float e2v = __expf(__builtin_fmaf(v[j], 2.f, bv2[j]));
        float eng = __expf(__builtin_fmaf(g[j], -1.f, bgn[j]));
        res[j] = (e2v - 1.f) * rcp_((e2v + 1.f) * (1.f + eng));
      }
      __builtin_nontemporal_store(res, (f32x4*)(ob + (size_t)t * 512 + f0));
    }
  }
}

extern "C" void kernel_launch(void* const* d_in, const int* in_sizes, int n_in,
                              void* d_out, int out_size, void* d_ws, size_t ws_size,
                              hipStream_t stream) {
  const float* x  = (const float*)d_in[0];
  const float* Wv = (const float*)d_in[1];
  const float* bv = (const float*)d_in[2];
  const float* Wg = (const float*)d_in[3];
  const float* bg = (const float*)d_in[4];
  const int* dil  = (const int*)d_in[5];
  float* out = (float*)d_out;

  short* wimg = (short*)d_ws;                          // 512 KiB weight image
  float* bcat = (float*)((char*)d_ws + 16 * 32768);    // 2 KiB biases

  prep_weights<<<1024, 256, 0, stream>>>(Wv, Wg, bv, bg, wimg, bcat);
  snail_main<<<B_ * (T_ / BM), 512, 0, stream>>>(x, wimg, bcat, dil, out);
}